// Round 3
// baseline (459.480 us; speedup 1.0000x reference)
//
#include <hip/hip_runtime.h>
#include <math.h>

typedef __bf16 bf16;
typedef __bf16 bf16x8 __attribute__((ext_vector_type(8)));
typedef __bf16 bf16x4 __attribute__((ext_vector_type(4)));
typedef float f32x4 __attribute__((ext_vector_type(4)));

#define DEV static __device__ __forceinline__

constexpr int kBatch = 4, kSeq = 2048, kDModel = 1024;
constexpr int kDInner = 2048, kHeads = 32;
constexpr int kConvDim = 2176, kDInProj = 4256, kNPad1 = 4352;
constexpr int kRows = kBatch * kSeq; // 8192
constexpr int kChunk = 64, kNChunk = kSeq / kChunk; // 32
constexpr float kRmsEps = 1.1920929e-07f;
constexpr float kGnEps = 1e-5f;

DEV float siluf(float x) { return x / (1.f + expf(-x)); }

DEV float block_reduce_sum(float v, float* red, int tid) {
#pragma unroll
  for (int m = 1; m < 64; m <<= 1) v += __shfl_xor(v, m);
  if ((tid & 63) == 0) red[tid >> 6] = v;
  __syncthreads();
  return red[0] + red[1] + red[2] + red[3];
}

// ---------------- RMSNorm (writes bf16 x_norm) ----------------
__global__ __launch_bounds__(256) void k_rmsnorm(const float* __restrict__ x,
                                                 const float* __restrict__ nw,
                                                 bf16* __restrict__ xnb) {
  const int row = blockIdx.x;
  const int tid = threadIdx.x;
  float4 v = ((const float4*)(x + (size_t)row * kDModel))[tid];
  __shared__ float red[4];
  float ss = block_reduce_sum(v.x * v.x + v.y * v.y + v.z * v.z + v.w * v.w, red, tid);
  float scale = rsqrtf(ss * (1.f / kDModel) + kRmsEps);
  float4 wv = ((const float4*)nw)[tid];
  bf16x4 ov;
  ov[0] = (bf16)(v.x * scale * wv.x);
  ov[1] = (bf16)(v.y * scale * wv.y);
  ov[2] = (bf16)(v.z * scale * wv.z);
  ov[3] = (bf16)(v.w * scale * wv.w);
  *(bf16x4*)(xnb + (size_t)row * kDModel + tid * 4) = ov;
}

// ---------------- mean pool over S (deterministic 2-stage) ----------------
__global__ __launch_bounds__(128) void k_pool1(const bf16* __restrict__ xnb,
                                               float* __restrict__ part) {
  const int g = blockIdx.x, b = blockIdx.y;
  const int tid = threadIdx.x;
  const bf16* base = xnb + ((size_t)b * kSeq + (size_t)g * 32) * kDModel + tid * 8;
  float acc[8] = {0, 0, 0, 0, 0, 0, 0, 0};
  for (int r = 0; r < 32; ++r) {
    bf16x8 v = *(const bf16x8*)(base + (size_t)r * kDModel);
#pragma unroll
    for (int j = 0; j < 8; ++j) acc[j] += (float)v[j];
  }
  float* o = part + ((size_t)b * 64 + g) * kDModel + tid * 8;
#pragma unroll
  for (int j = 0; j < 8; ++j) o[j] = acc[j];
}

__global__ __launch_bounds__(256) void k_pool2(const float* __restrict__ part,
                                               float* __restrict__ mean) {
  const int idx = blockIdx.x * 256 + threadIdx.x; // 4096
  const int b = idx >> 10, d = idx & 1023;
  float s = 0.f;
  for (int g = 0; g < 64; ++g) s += part[((size_t)b * 64 + g) * kDModel + d];
  mean[idx] = s * (1.f / kSeq);
}

// ---------------- router MLP + softmax ----------------
__global__ __launch_bounds__(128) void k_router(const float* __restrict__ mean,
                                                const float* __restrict__ w1,
                                                const float* __restrict__ b1,
                                                const float* __restrict__ w2,
                                                const float* __restrict__ b2,
                                                float* __restrict__ pfm) {
  __shared__ float hbuf[4][32];
  __shared__ float logit[4][3];
  const int t = threadIdx.x;
  {
    int b = t >> 5, j = t & 31;
    float s = b1[j];
    for (int d = 0; d < kDModel; ++d) s += mean[b * kDModel + d] * w1[j * kDModel + d];
    hbuf[b][j] = siluf(s);
  }
  __syncthreads();
  if (t < 12) {
    int b = t / 3, k = t % 3;
    float s = b2[k];
    for (int j = 0; j < 32; ++j) s += hbuf[b][j] * w2[k * 32 + j];
    logit[b][k] = s;
  }
  __syncthreads();
  if (t < 4) {
    float m = fmaxf(logit[t][0], fmaxf(logit[t][1], logit[t][2]));
    float e0 = expf(logit[t][0] - m), e1 = expf(logit[t][1] - m), e2 = expf(logit[t][2] - m);
    float inv = 1.f / (e0 + e1 + e2);
    pfm[t] = e0 * inv;            // p_fast[b]
    pfm[4 + t] = (e1 + e2) * inv; // p_mamba[b]
  }
}

// ---------------- weight casts ----------------
__global__ __launch_bounds__(256) void k_castpad_w1(const float* __restrict__ w,
                                                    bf16* __restrict__ wb) {
  const size_t idx = (size_t)blockIdx.x * 256 + threadIdx.x; // over 4352*1024
  const int row = (int)(idx >> 10);
  wb[idx] = (bf16)(row < kDInProj ? w[idx] : 0.f);
}

__global__ __launch_bounds__(256) void k_cast_w2(const float* __restrict__ w,
                                                 bf16* __restrict__ wb) {
  const size_t i4 = (size_t)blockIdx.x * 256 + threadIdx.x;
  float4 v = ((const float4*)w)[i4];
  bf16x4 o;
  o[0] = (bf16)v.x; o[1] = (bf16)v.y; o[2] = (bf16)v.z; o[3] = (bf16)v.w;
  ((bf16x4*)wb)[i4] = o;
}

// ====== 256x256 bf16 GEMM, BK=32, 8 waves, triple-buffered counted-vmcnt ======
// C[m][n] = sum_k A[m,k]*B[n,k]; A [M,K], B [Npad,K] row-major bf16.
// Grid linear = ntm*ntn (multiple of 8), 512 threads.
// Pipeline: stage(kt+2) -> vmcnt(8) -> barrier -> ds_read(kt) -> lgkmcnt(0)
//           -> barrier -> MFMA. Loads never drain to 0 mid-loop (T4).
__global__ __launch_bounds__(512, 2) void k_gemm256(
    const bf16* __restrict__ A, const bf16* __restrict__ B,
    float* __restrict__ Cf, bf16* __restrict__ Cb,
    int K, int Nreal, int ldc, int ntn, int outBf16) {
  __shared__ bf16 lds[3][2][256 * 32]; // 96 KB: 3 bufs x {A,B} x 256x32
  const int tid = threadIdx.x;
  const int lane = tid & 63, wid = tid >> 6;
  const int wr = wid >> 2, wc = wid & 3;    // 2x4 wave grid, wave out = 128x64
  const int lr = lane & 15, kb = lane >> 4; // frag row, 8-elem k chunk
  // bijective XCD swizzle (gridDim.x % 8 == 0)
  const int cpx = (int)gridDim.x >> 3;
  const int bid = ((int)blockIdx.x & 7) * cpx + ((int)blockIdx.x >> 3);
  const long n0 = (long)(bid % ntn) * 256;
  const long m0 = (long)(bid / ntn) * 256;

  f32x4 acc[8][4];
#pragma unroll
  for (int i = 0; i < 8; ++i)
#pragma unroll
    for (int j = 0; j < 4; ++j) acc[i][j] = (f32x4){0.f, 0.f, 0.f, 0.f};

  const int nkt = K >> 5;

  // stage K-step kt into buffer bufi: 4 global_load_lds x 16B per thread
#define STAGE(bufi, kt)                                                        \
  {                                                                            \
    const long koff = (long)(kt)*32;                                           \
    _Pragma("unroll") for (int j = 0; j < 2; ++j) {                            \
      int idx = j * 512 + tid;                                                 \
      int row = idx >> 2, cw = idx & 3;                                        \
      __builtin_amdgcn_global_load_lds(                                        \
          (const __attribute__((address_space(1))) void*)(A + (m0 + row) * K + \
                                                          koff + cw * 8),      \
          (__attribute__((address_space(3))) void*)((char*)&lds[bufi][0][0] +  \
                                                    idx * 16),                 \
          16, 0, 0);                                                           \
    }                                                                          \
    _Pragma("unroll") for (int j = 0; j < 2; ++j) {                            \
      int idx = j * 512 + tid;                                                 \
      int row = idx >> 2, cw = idx & 3;                                        \
      __builtin_amdgcn_global_load_lds(                                        \
          (const __attribute__((address_space(1))) void*)(B + (n0 + row) * K + \
                                                          koff + cw * 8),      \
          (__attribute__((address_space(3))) void*)((char*)&lds[bufi][1][0] +  \
                                                    idx * 16),                 \
          16, 0, 0);                                                           \
    }                                                                          \
  }

  STAGE(0, 0);
  STAGE(1, 1);

  for (int kt = 0; kt < nkt; ++kt) {
    const int cur = kt % 3;
    if (kt + 2 < nkt) {
      const int nxt = (kt + 2) % 3;
      STAGE(nxt, kt + 2);
      asm volatile("s_waitcnt vmcnt(8)" ::: "memory");
    } else if (kt + 1 < nkt) {
      asm volatile("s_waitcnt vmcnt(4)" ::: "memory");
    } else {
      asm volatile("s_waitcnt vmcnt(0)" ::: "memory");
    }
    __builtin_amdgcn_s_barrier(); // all waves' stage(kt) landed

    const bf16* Abase = &lds[cur][0][0];
    const bf16* Bbase = &lds[cur][1][0];
    bf16x8 af[8], bv[4];
#pragma unroll
    for (int mf = 0; mf < 8; ++mf)
      af[mf] = *(const bf16x8*)(Abase + (wr * 128 + mf * 16 + lr) * 32 + kb * 8);
#pragma unroll
    for (int nf = 0; nf < 4; ++nf)
      bv[nf] = *(const bf16x8*)(Bbase + (wc * 64 + nf * 16 + lr) * 32 + kb * 8);
    asm volatile("s_waitcnt lgkmcnt(0)" ::: "memory"); // reads complete
    __builtin_amdgcn_s_barrier(); // => safe to overwrite buf (kt)%3 next iters

    __builtin_amdgcn_s_setprio(1);
#pragma unroll
    for (int mf = 0; mf < 8; ++mf)
#pragma unroll
      for (int nf = 0; nf < 4; ++nf)
        acc[mf][nf] =
            __builtin_amdgcn_mfma_f32_16x16x32_bf16(af[mf], bv[nf], acc[mf][nf], 0, 0, 0);
    __builtin_amdgcn_s_setprio(0);
  }
#undef STAGE

  const int rr = kb * 4;
#pragma unroll
  for (int mf = 0; mf < 8; ++mf) {
#pragma unroll
    for (int nf = 0; nf < 4; ++nf) {
      int col = (int)n0 + wc * 64 + nf * 16 + lr;
      if (col < Nreal) {
        long rbase = m0 + wr * 128 + mf * 16 + rr;
#pragma unroll
        for (int j = 0; j < 4; ++j) {
          float v = acc[mf][nf][j];
          if (outBf16) Cb[(rbase + j) * (long)ldc + col] = (bf16)v;
          else Cf[(rbase + j) * (long)ldc + col] = v;
        }
      }
    }
  }
}

// ---------------- causal depthwise conv1d (k=4) + bias + SiLU -> bf16 -------
__global__ __launch_bounds__(256) void k_conv(const bf16* __restrict__ zx,
                                              const float* __restrict__ cw,
                                              const float* __restrict__ cb,
                                              bf16* __restrict__ xbc) {
  const int row = blockIdx.x;
  const int c = blockIdx.y * 256 + threadIdx.x;
  if (c >= kConvDim) return;
  const int s = row & (kSeq - 1);
  const bf16* col = zx + (size_t)row * kDInProj + kDInner + c;
  float acc = cb[c];
  const float w0 = cw[c * 4], w1 = cw[c * 4 + 1], w2 = cw[c * 4 + 2], w3 = cw[c * 4 + 3];
  float v3 = (float)col[0];
  float v2 = (s >= 1) ? (float)col[-(ptrdiff_t)kDInProj] : 0.f;
  float v1 = (s >= 2) ? (float)col[-2 * (ptrdiff_t)kDInProj] : 0.f;
  float v0 = (s >= 3) ? (float)col[-3 * (ptrdiff_t)kDInProj] : 0.f;
  acc += w0 * v0 + w1 * v1 + w2 * v2 + w3 * v3;
  xbc[(size_t)row * kConvDim + c] = (bf16)siluf(acc);
}

// ---------------- dt = softplus, ldA = dt*A (log decay) ----------------
__global__ __launch_bounds__(256) void k_dtda(const bf16* __restrict__ zx,
                                              const float* __restrict__ dt_bias,
                                              const float* __restrict__ A_log,
                                              float* __restrict__ dt, float* __restrict__ ldA) {
  const int idx = blockIdx.x * 256 + threadIdx.x;
  const int row = idx >> 5, hh = idx & 31;
  float raw = (float)zx[(size_t)row * kDInProj + (kDInner + kConvDim) + hh] + dt_bias[hh];
  float dtv = (raw > 20.f) ? raw : log1pf(expf(raw));
  dt[idx] = dtv;
  ldA[idx] = dtv * -expf(A_log[hh]);
}

// ================= chunked SSD scan =================
__global__ __launch_bounds__(256) void k_chunkA(
    const bf16* __restrict__ xbc, const float* __restrict__ dtb,
    const float* __restrict__ ldab, float* __restrict__ cumbuf,
    float* __restrict__ Tc, bf16* __restrict__ yb, float* __restrict__ Sbuf) {
  const int c = blockIdx.x, h = blockIdx.y, b = blockIdx.z;
  const int tid = threadIdx.x;
  const int w = tid >> 6, lane = tid & 63, lr = lane & 15, kb = lane >> 4;
  const int rr = kb * 4;
  const int t0 = c * kChunk;
  __shared__ bf16 Bl[64 * 72], Cl[64 * 72], XT[64 * 72], WBT[64 * 72], Ml[64 * 72];
  __shared__ float cum_s[64], dt_s[64], w_s[64];

  { // stage B, C (row-major) and X^T
    int s = tid >> 2, q = tid & 3;
    const bf16* rowp = xbc + ((size_t)b * kSeq + t0 + s) * kConvDim;
    bf16x8 x0 = *(const bf16x8*)(rowp + h * 64 + q * 16);
    bf16x8 x1 = *(const bf16x8*)(rowp + h * 64 + q * 16 + 8);
    bf16x8 b0 = *(const bf16x8*)(rowp + kDInner + q * 16);
    bf16x8 b1 = *(const bf16x8*)(rowp + kDInner + q * 16 + 8);
    bf16x8 c0 = *(const bf16x8*)(rowp + kDInner + 64 + q * 16);
    bf16x8 c1 = *(const bf16x8*)(rowp + kDInner + 64 + q * 16 + 8);
    *(bf16x8*)(Bl + s * 72 + q * 16) = b0;
    *(bf16x8*)(Bl + s * 72 + q * 16 + 8) = b1;
    *(bf16x8*)(Cl + s * 72 + q * 16) = c0;
    *(bf16x8*)(Cl + s * 72 + q * 16 + 8) = c1;
#pragma unroll
    for (int e = 0; e < 8; ++e) XT[(q * 16 + e) * 72 + s] = x0[e];
#pragma unroll
    for (int e = 0; e < 8; ++e) XT[(q * 16 + 8 + e) * 72 + s] = x1[e];
  }
  if (tid < 64) { // wave 0: inclusive prefix of ldA
    size_t di = ((size_t)b * kSeq + t0 + tid) * kHeads + h;
    float v = ldab[di];
    float dtv = dtb[di];
#pragma unroll
    for (int o = 1; o < 64; o <<= 1) {
      float u = __shfl_up(v, o);
      if (lane >= o) v += u;
    }
    cum_s[tid] = v;
    dt_s[tid] = dtv;
    float tot = __shfl(v, 63);
    w_s[tid] = expf(tot - v) * dtv;
    cumbuf[(((size_t)b * kHeads + h) * kNChunk + c) * 64 + tid] = v;
    if (tid == 63) Tc[(b * kHeads + h) * kNChunk + c] = expf(v);
  }
  __syncthreads();

  // WBT[n][s] = B[s][n] * w[s]
#pragma unroll
  for (int i = 0; i < 16; ++i) {
    int e = i * 256 + tid;
    int n = e >> 6, s = e & 63;
    WBT[n * 72 + s] = (bf16)((float)Bl[s * 72 + n] * w_s[s]);
  }

  // GEMM1: G[t,s] = sum_n C[t,n] B[s,n]
  f32x4 g[4];
#pragma unroll
  for (int nt = 0; nt < 4; ++nt) g[nt] = (f32x4){0.f, 0.f, 0.f, 0.f};
#pragma unroll
  for (int kk = 0; kk < 2; ++kk) {
    bf16x8 a = *(const bf16x8*)(Cl + (w * 16 + lr) * 72 + kk * 32 + kb * 8);
#pragma unroll
    for (int nt = 0; nt < 4; ++nt) {
      bf16x8 bb = *(const bf16x8*)(Bl + (nt * 16 + lr) * 72 + kk * 32 + kb * 8);
      g[nt] = __builtin_amdgcn_mfma_f32_16x16x32_bf16(a, bb, g[nt], 0, 0, 0);
    }
  }
#pragma unroll
  for (int nt = 0; nt < 4; ++nt)
#pragma unroll
    for (int j = 0; j < 4; ++j) {
      int tt = w * 16 + rr + j, ss = nt * 16 + lr;
      float m = (ss <= tt) ? g[nt][j] * expf(cum_s[tt] - cum_s[ss]) * dt_s[ss] : 0.f;
      Ml[tt * 72 + ss] = (bf16)m;
    }
  __syncthreads();

  // GEMM2: Y_intra[t,p] = sum_s M[t,s] x[s,p]
  f32x4 y4[4];
#pragma unroll
  for (int pt = 0; pt < 4; ++pt) y4[pt] = (f32x4){0.f, 0.f, 0.f, 0.f};
#pragma unroll
  for (int kk = 0; kk < 2; ++kk) {
    bf16x8 a = *(const bf16x8*)(Ml + (w * 16 + lr) * 72 + kk * 32 + kb * 8);
#pragma unroll
    for (int pt = 0; pt < 4; ++pt) {
      bf16x8 bb = *(const bf16x8*)(XT + (pt * 16 + lr) * 72 + kk * 32 + kb * 8);
      y4[pt] = __builtin_amdgcn_mfma_f32_16x16x32_bf16(a, bb, y4[pt], 0, 0, 0);
    }
  }
#pragma unroll
  for (int pt = 0; pt < 4; ++pt)
#pragma unroll
    for (int j = 0; j < 4; ++j) {
      int tt = w * 16 + rr + j, pp = pt * 16 + lr;
      yb[((size_t)b * kSeq + t0 + tt) * kDInner + h * 64 + pp] = (bf16)y4[pt][j];
    }

  // GEMM3: S[p,n] = sum_s x[s,p] w[s] B[s,n]
  f32x4 s4[4];
#pragma unroll
  for (int nt = 0; nt < 4; ++nt) s4[nt] = (f32x4){0.f, 0.f, 0.f, 0.f};
#pragma unroll
  for (int kk = 0; kk < 2; ++kk) {
    bf16x8 a = *(const bf16x8*)(XT + (w * 16 + lr) * 72 + kk * 32 + kb * 8);
#pragma unroll
    for (int nt = 0; nt < 4; ++nt) {
      bf16x8 bb = *(const bf16x8*)(WBT + (nt * 16 + lr) * 72 + kk * 32 + kb * 8);
      s4[nt] = __builtin_amdgcn_mfma_f32_16x16x32_bf16(a, bb, s4[nt], 0, 0, 0);
    }
  }
  const size_t sbase = (((size_t)b * kHeads + h) * kNChunk + c) * 4096;
#pragma unroll
  for (int nt = 0; nt < 4; ++nt)
#pragma unroll
    for (int j = 0; j < 4; ++j) {
      int pp = w * 16 + rr + j, nn = nt * 16 + lr;
      Sbuf[sbase + pp * 64 + nn] = s4[nt][j];
    }
}

// Pass B: serial scan over 32 chunks, in-place: Sbuf[c] becomes h_start[c]
__global__ __launch_bounds__(256) void k_chunkB(float* __restrict__ S,
                                                const float* __restrict__ Tc) {
  const int gid = blockIdx.x * 256 + threadIdx.x;
  const int bh = gid >> 10;
  const int pn = (gid & 1023) << 2;
  float* base = S + (size_t)bh * kNChunk * 4096 + pn;
  const float* tc = Tc + bh * kNChunk;
  float4 hh = {0.f, 0.f, 0.f, 0.f};
  float4 s = *(const float4*)(base);
  for (int c = 0; c < kNChunk; ++c) {
    float4 sn = {0.f, 0.f, 0.f, 0.f};
    if (c + 1 < kNChunk) sn = *(const float4*)(base + (size_t)(c + 1) * 4096);
    float t = tc[c];
    *(float4*)(base + (size_t)c * 4096) = hh;
    hh.x = t * hh.x + s.x;
    hh.y = t * hh.y + s.y;
    hh.z = t * hh.z + s.z;
    hh.w = t * hh.w + s.w;
    s = sn;
  }
}

// Pass C: y += exp(cum[t]) * C[t]·h0[p,:] + D*x
__global__ __launch_bounds__(256) void k_chunkC(
    const bf16* __restrict__ xbc, const float* __restrict__ cumbuf,
    const float* __restrict__ hs, const float* __restrict__ Dp,
    bf16* __restrict__ yb) {
  const int c = blockIdx.x, h = blockIdx.y, b = blockIdx.z;
  const int tid = threadIdx.x;
  const int w = tid >> 6, lane = tid & 63, lr = lane & 15, kb = lane >> 4;
  const int rr = kb * 4;
  const int t0 = c * kChunk;
  __shared__ bf16 Cl[64 * 72];
  __shared__ float ecum[64];
  {
    int s = tid >> 2, q = tid & 3;
    const bf16* rowp = xbc + ((size_t)b * kSeq + t0 + s) * kConvDim + kDInner + 64 + q * 16;
    *(bf16x8*)(Cl + s * 72 + q * 16) = *(const bf16x8*)rowp;
    *(bf16x8*)(Cl + s * 72 + q * 16 + 8) = *(const bf16x8*)(rowp + 8);
  }
  if (tid < 64)
    ecum[tid] = expf(cumbuf[(((size_t)b * kHeads + h) * kNChunk + c) * 64 + tid]);
  __syncthreads();

  const float* hbase = hs + (((size_t)b * kHeads + h) * kNChunk + c) * 4096;
  f32x4 acc[4];
#pragma unroll
  for (int pt = 0; pt < 4; ++pt) acc[pt] = (f32x4){0.f, 0.f, 0.f, 0.f};
#pragma unroll
  for (int kk = 0; kk < 2; ++kk) {
    bf16x8 a = *(const bf16x8*)(Cl + (w * 16 + lr) * 72 + kk * 32 + kb * 8);
#pragma unroll
    for (int pt = 0; pt < 4; ++pt) {
      const float* hp = hbase + (pt * 16 + lr) * 64 + kk * 32 + kb * 8;
      float4 h0 = *(const float4*)hp;
      float4 h1 = *(const float4*)(hp + 4);
      bf16x8 bb;
      bb[0] = (bf16)h0.x; bb[1] = (bf16)h0.y; bb[2] = (bf16)h0.z; bb[3] = (bf16)h0.w;
      bb[4] = (bf16)h1.x; bb[5] = (bf16)h1.y; bb[6] = (bf16)h1.z; bb[7] = (bf16)h1.w;
      acc[pt] = __builtin_amdgcn_mfma_f32_16x16x32_bf16(a, bb, acc[pt], 0, 0, 0);
    }
  }
  const float Dh = Dp[h];
#pragma unroll
  for (int pt = 0; pt < 4; ++pt)
#pragma unroll
    for (int j = 0; j < 4; ++j) {
      int tt = w * 16 + rr + j, pp = pt * 16 + lr;
      size_t ri = (size_t)b * kSeq + t0 + tt;
      size_t yi = ri * kDInner + h * 64 + pp;
      float xv = (float)xbc[ri * kConvDim + h * 64 + pp];
      yb[yi] = (bf16)((float)yb[yi] + ecum[tt] * acc[pt][j] + Dh * xv);
    }
}

// ---------------- gated RMSNorm: yg = rmsnorm(y*silu(z)) * gw ----------------
__global__ __launch_bounds__(256) void k_gnorm(const bf16* __restrict__ y,
                                               const bf16* __restrict__ zx,
                                               const float* __restrict__ gw,
                                               bf16* __restrict__ yg) {
  const int row = blockIdx.x;
  const int tid = threadIdx.x;
  const int c0 = tid * 8;
  bf16x8 yv = *(const bf16x8*)(y + (size_t)row * kDInner + c0);
  bf16x8 zv = *(const bf16x8*)(zx + (size_t)row * kDInProj + c0);
  float v[8];
  float ss = 0.f;
#pragma unroll
  for (int j = 0; j < 8; ++j) {
    float val = (float)yv[j] * siluf((float)zv[j]);
    v[j] = val;
    ss += val * val;
  }
  __shared__ float red[4];
  ss = block_reduce_sum(ss, red, tid);
  float scale = rsqrtf(ss * (1.f / kDInner) + kGnEps);
  bf16x8 ov;
#pragma unroll
  for (int j = 0; j < 8; ++j) ov[j] = (bf16)(v[j] * scale * gw[c0 + j]);
  *(bf16x8*)(yg + (size_t)row * kDInner + c0) = ov;
}

// ---------------- final combine ----------------
__global__ __launch_bounds__(256) void k_combine(const float* __restrict__ x,
                                                 const float* __restrict__ nw,
                                                 const float* __restrict__ mo,
                                                 const float* __restrict__ pfm,
                                                 float* __restrict__ out) {
  const int row = blockIdx.x;
  const int tid = threadIdx.x;
  const int b = row >> 11;
  float4 v = ((const float4*)(x + (size_t)row * kDModel))[tid];
  __shared__ float red[4];
  float ss = block_reduce_sum(v.x * v.x + v.y * v.y + v.z * v.z + v.w * v.w, red, tid);
  float scale = rsqrtf(ss * (1.f / kDModel) + kRmsEps);
  float pf = pfm[b], pm = pfm[4 + b];
  float4 wv = ((const float4*)nw)[tid];
  float4 mv = ((const float4*)(mo + (size_t)row * kDModel))[tid];
  float4 o;
  o.x = v.x + pf * (v.x * scale * wv.x) + pm * mv.x;
  o.y = v.y + pf * (v.y * scale * wv.y) + pm * mv.y;
  o.z = v.z + pf * (v.z * scale * wv.z) + pm * mv.z;
  o.w = v.w + pf * (v.w * scale * wv.w) + pm * mv.w;
  ((float4*)(out + (size_t)row * kDModel))[tid] = o;
}

extern "C" void kernel_launch(void* const* d_in, const int* in_sizes, int n_in,
                              void* d_out, int out_size, void* d_ws, size_t ws_size,
                              hipStream_t stream) {
  const float* x = (const float*)d_in[0];
  const float* norm_w = (const float*)d_in[1];
  const float* r_w1 = (const float*)d_in[2];
  const float* r_b1 = (const float*)d_in[3];
  const float* r_w2 = (const float*)d_in[4];
  const float* r_b2 = (const float*)d_in[5];
  const float* in_proj_w = (const float*)d_in[6];
  const float* conv_w = (const float*)d_in[7];
  const float* conv_b = (const float*)d_in[8];
  const float* dt_bias = (const float*)d_in[9];
  const float* A_log = (const float*)d_in[10];
  const float* D_param = (const float*)d_in[11];
  const float* gnorm_w = (const float*)d_in[12];
  const float* out_proj_w = (const float*)d_in[13];
  float* out = (float*)d_out;
  char* ws = (char*)d_ws;

  // workspace layout (~240.2 MB)
  bf16* xnb     = (bf16*)(ws + 0);           // 16,777,216
  bf16* w1b     = (bf16*)(ws + 16777216);    //  8,912,896
  bf16* zx      = (bf16*)(ws + 25690112);    // 69,730,304
  bf16* xbc     = (bf16*)(ws + 95420416);    // 35,651,584
  float* dtb    = (float*)(ws + 131072000);  //  1,048,576
  float* ldab   = (float*)(ws + 132120576);  //  1,048,576
  float* cumbuf = (float*)(ws + 133169152);  //  1,048,576
  float* Tcb    = (float*)(ws + 134217728);  //     16,384
  bf16* yb      = (bf16*)(ws + 134234112);   // 33,554,432
  float* Sbuf   = (float*)(ws + 167788544);  // 67,108,864
  bf16* yg      = (bf16*)(ws + 167788544);   // aliases Sbuf (dead after passC)
  bf16* w2b     = (bf16*)(ws + 234897408);   //  4,194,304
  float* part   = (float*)(ws + 239091712);  //  1,048,576
  float* meanb  = (float*)(ws + 240140288);  //     16,384
  float* pfm    = (float*)(ws + 240156672);  //         32
  float* mo     = (float*)(ws + 95420416);   // aliases xbc (dead after passC)

  k_rmsnorm<<<kRows, 256, 0, stream>>>(x, norm_w, xnb);
  k_pool1<<<dim3(64, 4), 128, 0, stream>>>(xnb, part);
  k_pool2<<<16, 256, 0, stream>>>(part, meanb);
  k_router<<<1, 128, 0, stream>>>(meanb, r_w1, r_b1, r_w2, r_b2, pfm);
  k_castpad_w1<<<kNPad1 * kDModel / 256, 256, 0, stream>>>(in_proj_w, w1b);
  k_cast_w2<<<kDModel * kDInner / 1024, 256, 0, stream>>>(out_proj_w, w2b);
  // zxbcdt = x_norm @ in_proj_w.T  [8192 x 4256] bf16 ; grid 32*17=544 (%8==0)
  k_gemm256<<<(kRows / 256) * (kNPad1 / 256), 512, 0, stream>>>(
      xnb, w1b, nullptr, zx, kDModel, kDInProj, kDInProj, kNPad1 / 256, 1);
  k_conv<<<dim3(kRows, 9), 256, 0, stream>>>(zx, conv_w, conv_b, xbc);
  k_dtda<<<kRows * kHeads / 256, 256, 0, stream>>>(zx, dt_bias, A_log, dtb, ldab);
  k_chunkA<<<dim3(kNChunk, kHeads, kBatch), 256, 0, stream>>>(
      xbc, dtb, ldab, cumbuf, Tcb, yb, Sbuf);
  k_chunkB<<<512, 256, 0, stream>>>(Sbuf, Tcb);
  k_chunkC<<<dim3(kNChunk, kHeads, kBatch), 256, 0, stream>>>(
      xbc, cumbuf, Sbuf, D_param, yb);
  k_gnorm<<<kRows, 256, 0, stream>>>(yb, zx, gnorm_w, yg);
  // mamba_out = yg @ out_proj_w.T  [8192 x 1024] f32 ; grid 32*4=128 (%8==0)
  k_gemm256<<<(kRows / 256) * (kDModel / 256), 512, 0, stream>>>(
      yg, w2b, mo, nullptr, kDInner, kDModel, kDModel, kDModel / 256, 0);
  k_combine<<<kRows, 256, 0, stream>>>(x, norm_w, mo, pfm, out);
}

// Round 4
// 355.902 us; speedup vs baseline: 1.2910x; 1.2910x over previous
//
#include <hip/hip_runtime.h>
#include <math.h>

typedef __bf16 bf16;
typedef __bf16 bf16x8 __attribute__((ext_vector_type(8)));
typedef __bf16 bf16x4 __attribute__((ext_vector_type(4)));
typedef float f32x4 __attribute__((ext_vector_type(4)));

#define DEV static __device__ __forceinline__
#define AS1 __attribute__((address_space(1)))
#define AS3 __attribute__((address_space(3)))

constexpr int kBatch = 4, kSeq = 2048, kDModel = 1024;
constexpr int kDInner = 2048, kHeads = 32;
constexpr int kConvDim = 2176, kDInProj = 4256, kNPad1 = 4352;
constexpr int kRows = kBatch * kSeq; // 8192
constexpr int kChunk = 64, kNChunk = kSeq / kChunk; // 32
constexpr float kRmsEps = 1.1920929e-07f;
constexpr float kGnEps = 1e-5f;

DEV float siluf(float x) { return x / (1.f + expf(-x)); }

DEV float block_reduce_sum(float v, float* red, int tid) {
#pragma unroll
  for (int m = 1; m < 64; m <<= 1) v += __shfl_xor(v, m);
  if ((tid & 63) == 0) red[tid >> 6] = v;
  __syncthreads();
  return red[0] + red[1] + red[2] + red[3];
}

// ---------------- RMSNorm (writes bf16 x_norm) ----------------
__global__ __launch_bounds__(256) void k_rmsnorm(const float* __restrict__ x,
                                                 const float* __restrict__ nw,
                                                 bf16* __restrict__ xnb) {
  const int row = blockIdx.x;
  const int tid = threadIdx.x;
  float4 v = ((const float4*)(x + (size_t)row * kDModel))[tid];
  __shared__ float red[4];
  float ss = block_reduce_sum(v.x * v.x + v.y * v.y + v.z * v.z + v.w * v.w, red, tid);
  float scale = rsqrtf(ss * (1.f / kDModel) + kRmsEps);
  float4 wv = ((const float4*)nw)[tid];
  bf16x4 ov;
  ov[0] = (bf16)(v.x * scale * wv.x);
  ov[1] = (bf16)(v.y * scale * wv.y);
  ov[2] = (bf16)(v.z * scale * wv.z);
  ov[3] = (bf16)(v.w * scale * wv.w);
  *(bf16x4*)(xnb + (size_t)row * kDModel + tid * 4) = ov;
}

// ---------------- mean pool over S (deterministic 2-stage) ----------------
__global__ __launch_bounds__(128) void k_pool1(const bf16* __restrict__ xnb,
                                               float* __restrict__ part) {
  const int g = blockIdx.x, b = blockIdx.y;
  const int tid = threadIdx.x;
  const bf16* base = xnb + ((size_t)b * kSeq + (size_t)g * 32) * kDModel + tid * 8;
  float acc[8] = {0, 0, 0, 0, 0, 0, 0, 0};
  for (int r = 0; r < 32; ++r) {
    bf16x8 v = *(const bf16x8*)(base + (size_t)r * kDModel);
#pragma unroll
    for (int j = 0; j < 8; ++j) acc[j] += (float)v[j];
  }
  float* o = part + ((size_t)b * 64 + g) * kDModel + tid * 8;
#pragma unroll
  for (int j = 0; j < 8; ++j) o[j] = acc[j];
}

__global__ __launch_bounds__(256) void k_pool2(const float* __restrict__ part,
                                               float* __restrict__ mean) {
  const int idx = blockIdx.x * 256 + threadIdx.x; // 4096
  const int b = idx >> 10, d = idx & 1023;
  float s = 0.f;
  for (int g = 0; g < 64; ++g) s += part[((size_t)b * 64 + g) * kDModel + d];
  mean[idx] = s * (1.f / kSeq);
}

// ---------------- router MLP + softmax ----------------
__global__ __launch_bounds__(128) void k_router(const float* __restrict__ mean,
                                                const float* __restrict__ w1,
                                                const float* __restrict__ b1,
                                                const float* __restrict__ w2,
                                                const float* __restrict__ b2,
                                                float* __restrict__ pfm) {
  __shared__ float hbuf[4][32];
  __shared__ float logit[4][3];
  const int t = threadIdx.x;
  {
    int b = t >> 5, j = t & 31;
    float s = b1[j];
    for (int d = 0; d < kDModel; ++d) s += mean[b * kDModel + d] * w1[j * kDModel + d];
    hbuf[b][j] = siluf(s);
  }
  __syncthreads();
  if (t < 12) {
    int b = t / 3, k = t % 3;
    float s = b2[k];
    for (int j = 0; j < 32; ++j) s += hbuf[b][j] * w2[k * 32 + j];
    logit[b][k] = s;
  }
  __syncthreads();
  if (t < 4) {
    float m = fmaxf(logit[t][0], fmaxf(logit[t][1], logit[t][2]));
    float e0 = expf(logit[t][0] - m), e1 = expf(logit[t][1] - m), e2 = expf(logit[t][2] - m);
    float inv = 1.f / (e0 + e1 + e2);
    pfm[t] = e0 * inv;            // p_fast[b]
    pfm[4 + t] = (e1 + e2) * inv; // p_mamba[b]
  }
}

// ---------------- weight casts ----------------
__global__ __launch_bounds__(256) void k_castpad_w1(const float* __restrict__ w,
                                                    bf16* __restrict__ wb) {
  const size_t idx = (size_t)blockIdx.x * 256 + threadIdx.x; // over 4352*1024
  const int row = (int)(idx >> 10);
  wb[idx] = (bf16)(row < kDInProj ? w[idx] : 0.f);
}

__global__ __launch_bounds__(256) void k_cast_w2(const float* __restrict__ w,
                                                 bf16* __restrict__ wb) {
  const size_t i4 = (size_t)blockIdx.x * 256 + threadIdx.x;
  float4 v = ((const float4*)w)[i4];
  bf16x4 o;
  o[0] = (bf16)v.x; o[1] = (bf16)v.y; o[2] = (bf16)v.z; o[3] = (bf16)v.w;
  ((bf16x4*)wb)[i4] = o;
}

// ====== bf16 GEMM: C[m][n] = sum_k A[m,k]*B[n,k], BK=64, dbuf, swizzled ======
// MF = m-frags per wave (8 -> BM=256, 4 -> BM=128). BN=256, 8 waves (2x4),
// 512 thr. One __syncthreads per K-tile; 64 (or 32) MFMA per barrier with
// ds_reads pipelined between MFMA quads. LDS XOR-swizzle (chunk ^= row&7):
// linear LDS dest + inverse-swizzled global source + swizzled ds_read.
template <int MF>
__global__ __launch_bounds__(512, 2) void k_gemm(
    const bf16* __restrict__ A, const bf16* __restrict__ B,
    bf16* __restrict__ Cb, float* __restrict__ Cf,
    int K, int Nreal, int ldc, int ntn, int outBf16) {
  constexpr int BM = MF * 32;
  constexpr int GM = MF / 4; // m-frags per phase group
  __shared__ __align__(16) bf16 Al[2][BM][64];
  __shared__ __align__(16) bf16 Bl[2][256][64];
  const int tid = threadIdx.x;
  const int lane = tid & 63, wid = tid >> 6;
  const int wr = wid >> 2, wc = wid & 3;
  const int lr = lane & 15, kb = lane >> 4;
  const int cpx = (int)gridDim.x >> 3;
  const int bid = ((int)blockIdx.x & 7) * cpx + ((int)blockIdx.x >> 3);
  const long n0 = (long)(bid % ntn) * 256;
  const long m0 = (long)(bid / ntn) * BM;

  f32x4 acc[MF][4];
#pragma unroll
  for (int i = 0; i < MF; ++i)
#pragma unroll
    for (int j = 0; j < 4; ++j) acc[i][j] = (f32x4){0.f, 0.f, 0.f, 0.f};

  const int nkt = K >> 6;

#define STAGE(pp, kt)                                                          \
  {                                                                            \
    const long koff = (long)(kt)*64;                                           \
    _Pragma("unroll") for (int j = 0; j < BM / 64; ++j) {                      \
      int idx = j * 512 + tid;                                                 \
      int row = idx >> 3, ch = idx & 7;                                        \
      int cs = ch ^ (row & 7);                                                 \
      __builtin_amdgcn_global_load_lds(                                        \
          (const AS1 void*)(A + (m0 + row) * K + koff + cs * 8),               \
          (AS3 void*)((char*)&Al[pp][0][0] + idx * 16), 16, 0, 0);             \
    }                                                                          \
    _Pragma("unroll") for (int j = 0; j < 4; ++j) {                            \
      int idx = j * 512 + tid;                                                 \
      int row = idx >> 3, ch = idx & 7;                                        \
      int cs = ch ^ (row & 7);                                                 \
      __builtin_amdgcn_global_load_lds(                                        \
          (const AS1 void*)(B + (n0 + row) * K + koff + cs * 8),               \
          (AS3 void*)((char*)&Bl[pp][0][0] + idx * 16), 16, 0, 0);             \
    }                                                                          \
  }
  // swizzled ds_read: global chunk g=(ks*4+kb) of row r lives at chunk g^(r&7)
#define RDA(pp, rrow, ks)                                                      \
  (*(const bf16x8*)((const char*)&Al[(pp)][0][0] + (rrow)*128 +                \
                    ((((ks)*4 + kb) ^ (lr & 7)) * 16)))
#define RDB(pp, rrow, ks)                                                      \
  (*(const bf16x8*)((const char*)&Bl[(pp)][0][0] + (rrow)*128 +                \
                    ((((ks)*4 + kb) ^ (lr & 7)) * 16)))

  bf16x8 bfr[4][2];
  bf16x8 afr[2][GM][2];

  STAGE(0, 0);
  __syncthreads(); // stage(0) landed (vmcnt0 drain inside)
#pragma unroll
  for (int nf = 0; nf < 4; ++nf)
#pragma unroll
    for (int ks = 0; ks < 2; ++ks) bfr[nf][ks] = RDB(0, wc * 64 + nf * 16 + lr, ks);
#pragma unroll
  for (int g = 0; g < GM; ++g)
#pragma unroll
    for (int ks = 0; ks < 2; ++ks) afr[0][g][ks] = RDA(0, wr * (MF * 16) + g * 16 + lr, ks);

  for (int t = 0; t < nkt; ++t) {
    const int p = t & 1;
    if (t + 1 < nkt) STAGE(p ^ 1, t + 1); // into buffer fully consumed at t-1
#pragma unroll
    for (int q = 0; q < 4; ++q) {
      if (q < 3) { // pipeline: read group q+1 while q computes
#pragma unroll
        for (int g = 0; g < GM; ++g)
#pragma unroll
          for (int ks = 0; ks < 2; ++ks)
            afr[(q + 1) & 1][g][ks] =
                RDA(p, wr * (MF * 16) + ((q + 1) * GM + g) * 16 + lr, ks);
      }
      __builtin_amdgcn_s_setprio(1);
#pragma unroll
      for (int g = 0; g < GM; ++g)
#pragma unroll
        for (int nf = 0; nf < 4; ++nf)
#pragma unroll
          for (int ks = 0; ks < 2; ++ks)
            acc[q * GM + g][nf] = __builtin_amdgcn_mfma_f32_16x16x32_bf16(
                afr[q & 1][g][ks], bfr[nf][ks], acc[q * GM + g][nf], 0, 0, 0);
      __builtin_amdgcn_s_setprio(0);
    }
    if (t + 1 < nkt) {
      __syncthreads(); // stage(t+1) landed; all waves done reading buf p
#pragma unroll
      for (int nf = 0; nf < 4; ++nf)
#pragma unroll
        for (int ks = 0; ks < 2; ++ks)
          bfr[nf][ks] = RDB(p ^ 1, wc * 64 + nf * 16 + lr, ks);
#pragma unroll
      for (int g = 0; g < GM; ++g)
#pragma unroll
        for (int ks = 0; ks < 2; ++ks)
          afr[0][g][ks] = RDA(p ^ 1, wr * (MF * 16) + g * 16 + lr, ks);
    }
  }
#undef STAGE
#undef RDA
#undef RDB

  const int rr = kb * 4;
#pragma unroll
  for (int mf = 0; mf < MF; ++mf) {
#pragma unroll
    for (int nf = 0; nf < 4; ++nf) {
      int col = (int)n0 + wc * 64 + nf * 16 + lr;
      if (col < Nreal) {
        long rbase = m0 + wr * (MF * 16) + mf * 16 + rr;
#pragma unroll
        for (int j = 0; j < 4; ++j) {
          float v = acc[mf][nf][j];
          if (outBf16) Cb[(rbase + j) * (long)ldc + col] = (bf16)v;
          else Cf[(rbase + j) * (long)ldc + col] = v;
        }
      }
    }
  }
}

// ------- causal depthwise conv1d (k=4) + bias + SiLU, vectorized bf16x8 -----
__global__ __launch_bounds__(256) void k_conv(const bf16* __restrict__ zx,
                                              const float* __restrict__ cw,
                                              const float* __restrict__ cb,
                                              bf16* __restrict__ xbc) {
  const int gid = blockIdx.x * 256 + threadIdx.x;
  if (gid >= kRows * 272) return; // 272 = 2176/8 chunks per row
  const int row = gid / 272;
  const int cg = gid - row * 272;
  const int c0 = cg * 8;
  const int s = row & (kSeq - 1);
  const bf16* base = zx + (size_t)row * kDInProj + kDInner + c0;
  bf16x8 z8 = {};
  bf16x8 r3 = *(const bf16x8*)(base);
  bf16x8 r2 = (s >= 1) ? *(const bf16x8*)(base - kDInProj) : z8;
  bf16x8 r1 = (s >= 2) ? *(const bf16x8*)(base - 2 * kDInProj) : z8;
  bf16x8 r0 = (s >= 3) ? *(const bf16x8*)(base - 3 * kDInProj) : z8;
  bf16x8 o;
#pragma unroll
  for (int e = 0; e < 8; ++e) {
    float4 w = ((const float4*)cw)[c0 + e];
    float a = cb[c0 + e] + w.x * (float)r0[e] + w.y * (float)r1[e] +
              w.z * (float)r2[e] + w.w * (float)r3[e];
    o[e] = (bf16)siluf(a);
  }
  *(bf16x8*)(xbc + (size_t)row * kConvDim + c0) = o;
}

// ---------------- dt = softplus, ldA = dt*A (log decay) ----------------
__global__ __launch_bounds__(256) void k_dtda(const bf16* __restrict__ zx,
                                              const float* __restrict__ dt_bias,
                                              const float* __restrict__ A_log,
                                              float* __restrict__ dt, float* __restrict__ ldA) {
  const int idx = blockIdx.x * 256 + threadIdx.x;
  const int row = idx >> 5, hh = idx & 31;
  float raw = (float)zx[(size_t)row * kDInProj + (kDInner + kConvDim) + hh] + dt_bias[hh];
  float dtv = (raw > 20.f) ? raw : log1pf(expf(raw));
  dt[idx] = dtv;
  ldA[idx] = dtv * -expf(A_log[hh]);
}

// ================= chunked SSD scan =================
__global__ __launch_bounds__(256) void k_chunkA(
    const bf16* __restrict__ xbc, const float* __restrict__ dtb,
    const float* __restrict__ ldab, float* __restrict__ cumbuf,
    float* __restrict__ Tc, bf16* __restrict__ yb, bf16* __restrict__ Sbuf) {
  const int c = blockIdx.x, h = blockIdx.y, b = blockIdx.z;
  const int tid = threadIdx.x;
  const int w = tid >> 6, lane = tid & 63, lr = lane & 15, kb = lane >> 4;
  const int rr = kb * 4;
  const int t0 = c * kChunk;
  __shared__ bf16 Bl[64 * 72], Cl[64 * 72], XT[64 * 72], WBT[64 * 72], Ml[64 * 72];
  __shared__ float cum_s[64], dt_s[64], w_s[64];

  { // stage B, C (row-major) and X^T
    int s = tid >> 2, q = tid & 3;
    const bf16* rowp = xbc + ((size_t)b * kSeq + t0 + s) * kConvDim;
    bf16x8 x0 = *(const bf16x8*)(rowp + h * 64 + q * 16);
    bf16x8 x1 = *(const bf16x8*)(rowp + h * 64 + q * 16 + 8);
    bf16x8 b0 = *(const bf16x8*)(rowp + kDInner + q * 16);
    bf16x8 b1 = *(const bf16x8*)(rowp + kDInner + q * 16 + 8);
    bf16x8 c0 = *(const bf16x8*)(rowp + kDInner + 64 + q * 16);
    bf16x8 c1 = *(const bf16x8*)(rowp + kDInner + 64 + q * 16 + 8);
    *(bf16x8*)(Bl + s * 72 + q * 16) = b0;
    *(bf16x8*)(Bl + s * 72 + q * 16 + 8) = b1;
    *(bf16x8*)(Cl + s * 72 + q * 16) = c0;
    *(bf16x8*)(Cl + s * 72 + q * 16 + 8) = c1;
#pragma unroll
    for (int e = 0; e < 8; ++e) XT[(q * 16 + e) * 72 + s] = x0[e];
#pragma unroll
    for (int e = 0; e < 8; ++e) XT[(q * 16 + 8 + e) * 72 + s] = x1[e];
  }
  if (tid < 64) { // wave 0: inclusive prefix of ldA
    size_t di = ((size_t)b * kSeq + t0 + tid) * kHeads + h;
    float v = ldab[di];
    float dtv = dtb[di];
#pragma unroll
    for (int o = 1; o < 64; o <<= 1) {
      float u = __shfl_up(v, o);
      if (lane >= o) v += u;
    }
    cum_s[tid] = v;
    dt_s[tid] = dtv;
    float tot = __shfl(v, 63);
    w_s[tid] = expf(tot - v) * dtv;
    cumbuf[(((size_t)b * kHeads + h) * kNChunk + c) * 64 + tid] = v;
    if (tid == 63) Tc[(b * kHeads + h) * kNChunk + c] = expf(v);
  }
  __syncthreads();

  // WBT[n][s] = B[s][n] * w[s]
#pragma unroll
  for (int i = 0; i < 16; ++i) {
    int e = i * 256 + tid;
    int n = e >> 6, s = e & 63;
    WBT[n * 72 + s] = (bf16)((float)Bl[s * 72 + n] * w_s[s]);
  }

  // GEMM1: G[t,s] = sum_n C[t,n] B[s,n]
  f32x4 g[4];
#pragma unroll
  for (int nt = 0; nt < 4; ++nt) g[nt] = (f32x4){0.f, 0.f, 0.f, 0.f};
#pragma unroll
  for (int kk = 0; kk < 2; ++kk) {
    bf16x8 a = *(const bf16x8*)(Cl + (w * 16 + lr) * 72 + kk * 32 + kb * 8);
#pragma unroll
    for (int nt = 0; nt < 4; ++nt) {
      bf16x8 bb = *(const bf16x8*)(Bl + (nt * 16 + lr) * 72 + kk * 32 + kb * 8);
      g[nt] = __builtin_amdgcn_mfma_f32_16x16x32_bf16(a, bb, g[nt], 0, 0, 0);
    }
  }
#pragma unroll
  for (int nt = 0; nt < 4; ++nt)
#pragma unroll
    for (int j = 0; j < 4; ++j) {
      int tt = w * 16 + rr + j, ss = nt * 16 + lr;
      float m = (ss <= tt) ? g[nt][j] * expf(cum_s[tt] - cum_s[ss]) * dt_s[ss] : 0.f;
      Ml[tt * 72 + ss] = (bf16)m;
    }
  __syncthreads();

  // GEMM2: Y_intra[t,p] = sum_s M[t,s] x[s,p]
  f32x4 y4[4];
#pragma unroll
  for (int pt = 0; pt < 4; ++pt) y4[pt] = (f32x4){0.f, 0.f, 0.f, 0.f};
#pragma unroll
  for (int kk = 0; kk < 2; ++kk) {
    bf16x8 a = *(const bf16x8*)(Ml + (w * 16 + lr) * 72 + kk * 32 + kb * 8);
#pragma unroll
    for (int pt = 0; pt < 4; ++pt) {
      bf16x8 bb = *(const bf16x8*)(XT + (pt * 16 + lr) * 72 + kk * 32 + kb * 8);
      y4[pt] = __builtin_amdgcn_mfma_f32_16x16x32_bf16(a, bb, y4[pt], 0, 0, 0);
    }
  }
#pragma unroll
  for (int pt = 0; pt < 4; ++pt)
#pragma unroll
    for (int j = 0; j < 4; ++j) {
      int tt = w * 16 + rr + j, pp = pt * 16 + lr;
      yb[((size_t)b * kSeq + t0 + tt) * kDInner + h * 64 + pp] = (bf16)y4[pt][j];
    }

  // GEMM3: S[p,n] = sum_s x[s,p] w[s] B[s,n]
  f32x4 s4[4];
#pragma unroll
  for (int nt = 0; nt < 4; ++nt) s4[nt] = (f32x4){0.f, 0.f, 0.f, 0.f};
#pragma unroll
  for (int kk = 0; kk < 2; ++kk) {
    bf16x8 a = *(const bf16x8*)(XT + (w * 16 + lr) * 72 + kk * 32 + kb * 8);
#pragma unroll
    for (int nt = 0; nt < 4; ++nt) {
      bf16x8 bb = *(const bf16x8*)(WBT + (nt * 16 + lr) * 72 + kk * 32 + kb * 8);
      s4[nt] = __builtin_amdgcn_mfma_f32_16x16x32_bf16(a, bb, s4[nt], 0, 0, 0);
    }
  }
  const size_t sbase = (((size_t)b * kHeads + h) * kNChunk + c) * 4096;
#pragma unroll
  for (int nt = 0; nt < 4; ++nt)
#pragma unroll
    for (int j = 0; j < 4; ++j) {
      int pp = w * 16 + rr + j, nn = nt * 16 + lr;
      Sbuf[sbase + pp * 64 + nn] = (bf16)s4[nt][j];
    }
}

// Pass B: serial scan over 32 chunks, in-place (bf16 states, fp32 accum)
__global__ __launch_bounds__(256) void k_chunkB(bf16* __restrict__ S,
                                                const float* __restrict__ Tc) {
  const int gid = blockIdx.x * 256 + threadIdx.x;
  const int bh = gid >> 10;
  const int pn = (gid & 1023) << 2;
  bf16* base = S + (size_t)bh * kNChunk * 4096 + pn;
  const float* tc = Tc + bh * kNChunk;
  float4 hh = {0.f, 0.f, 0.f, 0.f};
  bf16x4 s = *(const bf16x4*)(base);
  for (int c = 0; c < kNChunk; ++c) {
    bf16x4 sn = {};
    if (c + 1 < kNChunk) sn = *(const bf16x4*)(base + (size_t)(c + 1) * 4096);
    float t = tc[c];
    bf16x4 ho;
    ho[0] = (bf16)hh.x; ho[1] = (bf16)hh.y; ho[2] = (bf16)hh.z; ho[3] = (bf16)hh.w;
    *(bf16x4*)(base + (size_t)c * 4096) = ho;
    hh.x = t * hh.x + (float)s[0];
    hh.y = t * hh.y + (float)s[1];
    hh.z = t * hh.z + (float)s[2];
    hh.w = t * hh.w + (float)s[3];
    s = sn;
  }
}

// Pass C: y += exp(cum[t]) * C[t]·h0[p,:] + D*x
__global__ __launch_bounds__(256) void k_chunkC(
    const bf16* __restrict__ xbc, const float* __restrict__ cumbuf,
    const bf16* __restrict__ hs, const float* __restrict__ Dp,
    bf16* __restrict__ yb) {
  const int c = blockIdx.x, h = blockIdx.y, b = blockIdx.z;
  const int tid = threadIdx.x;
  const int w = tid >> 6, lane = tid & 63, lr = lane & 15, kb = lane >> 4;
  const int rr = kb * 4;
  const int t0 = c * kChunk;
  __shared__ bf16 Cl[64 * 72];
  __shared__ float ecum[64];
  {
    int s = tid >> 2, q = tid & 3;
    const bf16* rowp = xbc + ((size_t)b * kSeq + t0 + s) * kConvDim + kDInner + 64 + q * 16;
    *(bf16x8*)(Cl + s * 72 + q * 16) = *(const bf16x8*)rowp;
    *(bf16x8*)(Cl + s * 72 + q * 16 + 8) = *(const bf16x8*)(rowp + 8);
  }
  if (tid < 64)
    ecum[tid] = expf(cumbuf[(((size_t)b * kHeads + h) * kNChunk + c) * 64 + tid]);
  __syncthreads();

  const bf16* hbase = hs + (((size_t)b * kHeads + h) * kNChunk + c) * 4096;
  f32x4 acc[4];
#pragma unroll
  for (int pt = 0; pt < 4; ++pt) acc[pt] = (f32x4){0.f, 0.f, 0.f, 0.f};
#pragma unroll
  for (int kk = 0; kk < 2; ++kk) {
    bf16x8 a = *(const bf16x8*)(Cl + (w * 16 + lr) * 72 + kk * 32 + kb * 8);
#pragma unroll
    for (int pt = 0; pt < 4; ++pt) {
      bf16x8 bb = *(const bf16x8*)(hbase + (pt * 16 + lr) * 64 + kk * 32 + kb * 8);
      acc[pt] = __builtin_amdgcn_mfma_f32_16x16x32_bf16(a, bb, acc[pt], 0, 0, 0);
    }
  }
  const float Dh = Dp[h];
#pragma unroll
  for (int pt = 0; pt < 4; ++pt)
#pragma unroll
    for (int j = 0; j < 4; ++j) {
      int tt = w * 16 + rr + j, pp = pt * 16 + lr;
      size_t ri = (size_t)b * kSeq + t0 + tt;
      size_t yi = ri * kDInner + h * 64 + pp;
      float xv = (float)xbc[ri * kConvDim + h * 64 + pp];
      yb[yi] = (bf16)((float)yb[yi] + ecum[tt] * acc[pt][j] + Dh * xv);
    }
}

// ---------------- gated RMSNorm: yg = rmsnorm(y*silu(z)) * gw ----------------
__global__ __launch_bounds__(256) void k_gnorm(const bf16* __restrict__ y,
                                               const bf16* __restrict__ zx,
                                               const float* __restrict__ gw,
                                               bf16* __restrict__ yg) {
  const int row = blockIdx.x;
  const int tid = threadIdx.x;
  const int c0 = tid * 8;
  bf16x8 yv = *(const bf16x8*)(y + (size_t)row * kDInner + c0);
  bf16x8 zv = *(const bf16x8*)(zx + (size_t)row * kDInProj + c0);
  float v[8];
  float ss = 0.f;
#pragma unroll
  for (int j = 0; j < 8; ++j) {
    float val = (float)yv[j] * siluf((float)zv[j]);
    v[j] = val;
    ss += val * val;
  }
  __shared__ float red[4];
  ss = block_reduce_sum(ss, red, tid);
  float scale = rsqrtf(ss * (1.f / kDInner) + kGnEps);
  bf16x8 ov;
#pragma unroll
  for (int j = 0; j < 8; ++j) ov[j] = (bf16)(v[j] * scale * gw[c0 + j]);
  *(bf16x8*)(yg + (size_t)row * kDInner + c0) = ov;
}

// ---------------- final combine ----------------
__global__ __launch_bounds__(256) void k_combine(const float* __restrict__ x,
                                                 const float* __restrict__ nw,
                                                 const bf16* __restrict__ mo,
                                                 const float* __restrict__ pfm,
                                                 float* __restrict__ out) {
  const int row = blockIdx.x;
  const int tid = threadIdx.x;
  const int b = row >> 11;
  float4 v = ((const float4*)(x + (size_t)row * kDModel))[tid];
  __shared__ float red[4];
  float ss = block_reduce_sum(v.x * v.x + v.y * v.y + v.z * v.z + v.w * v.w, red, tid);
  float scale = rsqrtf(ss * (1.f / kDModel) + kRmsEps);
  float pf = pfm[b], pm = pfm[4 + b];
  float4 wv = ((const float4*)nw)[tid];
  bf16x4 mv = *(const bf16x4*)(mo + (size_t)row * kDModel + tid * 4);
  float4 o;
  o.x = v.x + pf * (v.x * scale * wv.x) + pm * (float)mv[0];
  o.y = v.y + pf * (v.y * scale * wv.y) + pm * (float)mv[1];
  o.z = v.z + pf * (v.z * scale * wv.z) + pm * (float)mv[2];
  o.w = v.w + pf * (v.w * scale * wv.w) + pm * (float)mv[3];
  ((float4*)(out + (size_t)row * kDModel))[tid] = o;
}

extern "C" void kernel_launch(void* const* d_in, const int* in_sizes, int n_in,
                              void* d_out, int out_size, void* d_ws, size_t ws_size,
                              hipStream_t stream) {
  const float* x = (const float*)d_in[0];
  const float* norm_w = (const float*)d_in[1];
  const float* r_w1 = (const float*)d_in[2];
  const float* r_b1 = (const float*)d_in[3];
  const float* r_w2 = (const float*)d_in[4];
  const float* r_b2 = (const float*)d_in[5];
  const float* in_proj_w = (const float*)d_in[6];
  const float* conv_w = (const float*)d_in[7];
  const float* conv_b = (const float*)d_in[8];
  const float* dt_bias = (const float*)d_in[9];
  const float* A_log = (const float*)d_in[10];
  const float* D_param = (const float*)d_in[11];
  const float* gnorm_w = (const float*)d_in[12];
  const float* out_proj_w = (const float*)d_in[13];
  float* out = (float*)d_out;
  char* ws = (char*)d_ws;

  // workspace layout (~207 MB)
  bf16* xnb     = (bf16*)(ws + 0);           // 16,777,216
  bf16* w1b     = (bf16*)(ws + 16777216);    //  8,912,896
  bf16* zx      = (bf16*)(ws + 25690112);    // 69,730,304
  bf16* xbc     = (bf16*)(ws + 95420416);    // 35,651,584
  float* dtb    = (float*)(ws + 131072000);  //  1,048,576
  float* ldab   = (float*)(ws + 132120576);  //  1,048,576
  float* cumbuf = (float*)(ws + 133169152);  //  1,048,576
  float* Tcb    = (float*)(ws + 134217728);  //     16,384
  bf16* yb      = (bf16*)(ws + 134234112);   // 33,554,432
  bf16* Sbuf    = (bf16*)(ws + 167788544);   // 33,554,432 (bf16 now)
  bf16* yg      = (bf16*)(ws + 167788544);   // aliases Sbuf (dead after passC)
  bf16* w2b     = (bf16*)(ws + 201342976);   //  4,194,304
  float* part   = (float*)(ws + 205537280);  //  1,048,576
  float* meanb  = (float*)(ws + 206585856);  //     16,384
  float* pfm    = (float*)(ws + 206602240);  //         32
  bf16* mo      = (bf16*)(ws + 95420416);    // aliases xbc (dead after passC)

  k_rmsnorm<<<kRows, 256, 0, stream>>>(x, norm_w, xnb);
  k_pool1<<<dim3(64, 4), 128, 0, stream>>>(xnb, part);
  k_pool2<<<16, 256, 0, stream>>>(part, meanb);
  k_router<<<1, 128, 0, stream>>>(meanb, r_w1, r_b1, r_w2, r_b2, pfm);
  k_castpad_w1<<<kNPad1 * kDModel / 256, 256, 0, stream>>>(in_proj_w, w1b);
  k_cast_w2<<<kDModel * kDInner / 1024, 256, 0, stream>>>(out_proj_w, w2b);
  // zxbcdt = x_norm @ in_proj_w.T  [8192 x 4256] bf16 ; grid 32*17=544 (%8==0)
  k_gemm<8><<<(kRows / 256) * (kNPad1 / 256), 512, 0, stream>>>(
      xnb, w1b, zx, nullptr, kDModel, kDInProj, kDInProj, kNPad1 / 256, 1);
  k_conv<<<kRows * 272 / 256, 256, 0, stream>>>(zx, conv_w, conv_b, xbc);
  k_dtda<<<kRows * kHeads / 256, 256, 0, stream>>>(zx, dt_bias, A_log, dtb, ldab);
  k_chunkA<<<dim3(kNChunk, kHeads, kBatch), 256, 0, stream>>>(
      xbc, dtb, ldab, cumbuf, Tcb, yb, Sbuf);
  k_chunkB<<<512, 256, 0, stream>>>(Sbuf, Tcb);
  k_chunkC<<<dim3(kNChunk, kHeads, kBatch), 256, 0, stream>>>(
      xbc, cumbuf, Sbuf, D_param, yb);
  k_gnorm<<<kRows, 256, 0, stream>>>(yb, zx, gnorm_w, yg);
  // mamba_out = yg @ out_proj_w.T  [8192 x 1024] bf16 ; grid 64*4=256 (%8==0)
  k_gemm<4><<<(kRows / 128) * (kDModel / 256), 512, 0, stream>>>(
      yg, w2b, mo, nullptr, kDInner, kDModel, kDModel, kDModel / 256, 1);
  k_combine<<<kRows, 256, 0, stream>>>(x, norm_w, mo, pfm, out);
}

// Round 5
// 355.523 us; speedup vs baseline: 1.2924x; 1.0011x over previous
//
#include <hip/hip_runtime.h>
#include <math.h>

typedef __bf16 bf16;
typedef __bf16 bf16x8 __attribute__((ext_vector_type(8)));
typedef __bf16 bf16x4 __attribute__((ext_vector_type(4)));
typedef float f32x4 __attribute__((ext_vector_type(4)));

#define DEV static __device__ __forceinline__
#define AS1 __attribute__((address_space(1)))
#define AS3 __attribute__((address_space(3)))

constexpr int kBatch = 4, kSeq = 2048, kDModel = 1024;
constexpr int kDInner = 2048, kHeads = 32;
constexpr int kConvDim = 2176, kDInProj = 4256, kNPad1 = 4352;
constexpr int kRows = kBatch * kSeq; // 8192
constexpr int kChunk = 64, kNChunk = kSeq / kChunk; // 32
constexpr float kRmsEps = 1.1920929e-07f;
constexpr float kGnEps = 1e-5f;

DEV float siluf(float x) { return x / (1.f + expf(-x)); }

DEV float block_reduce_sum(float v, float* red, int tid) {
#pragma unroll
  for (int m = 1; m < 64; m <<= 1) v += __shfl_xor(v, m);
  if ((tid & 63) == 0) red[tid >> 6] = v;
  __syncthreads();
  return red[0] + red[1] + red[2] + red[3];
}

// ---------------- RMSNorm (writes bf16 x_norm) ----------------
__global__ __launch_bounds__(256) void k_rmsnorm(const float* __restrict__ x,
                                                 const float* __restrict__ nw,
                                                 bf16* __restrict__ xnb) {
  const int row = blockIdx.x;
  const int tid = threadIdx.x;
  float4 v = ((const float4*)(x + (size_t)row * kDModel))[tid];
  __shared__ float red[4];
  float ss = block_reduce_sum(v.x * v.x + v.y * v.y + v.z * v.z + v.w * v.w, red, tid);
  float scale = rsqrtf(ss * (1.f / kDModel) + kRmsEps);
  float4 wv = ((const float4*)nw)[tid];
  bf16x4 ov;
  ov[0] = (bf16)(v.x * scale * wv.x);
  ov[1] = (bf16)(v.y * scale * wv.y);
  ov[2] = (bf16)(v.z * scale * wv.z);
  ov[3] = (bf16)(v.w * scale * wv.w);
  *(bf16x4*)(xnb + (size_t)row * kDModel + tid * 4) = ov;
}

// ---------------- mean pool over S (deterministic 2-stage) ----------------
__global__ __launch_bounds__(128) void k_pool1(const bf16* __restrict__ xnb,
                                               float* __restrict__ part) {
  const int g = blockIdx.x, b = blockIdx.y;
  const int tid = threadIdx.x;
  const bf16* base = xnb + ((size_t)b * kSeq + (size_t)g * 32) * kDModel + tid * 8;
  float acc[8] = {0, 0, 0, 0, 0, 0, 0, 0};
  for (int r = 0; r < 32; ++r) {
    bf16x8 v = *(const bf16x8*)(base + (size_t)r * kDModel);
#pragma unroll
    for (int j = 0; j < 8; ++j) acc[j] += (float)v[j];
  }
  float* o = part + ((size_t)b * 64 + g) * kDModel + tid * 8;
#pragma unroll
  for (int j = 0; j < 8; ++j) o[j] = acc[j];
}

__global__ __launch_bounds__(256) void k_pool2(const float* __restrict__ part,
                                               float* __restrict__ mean) {
  const int idx = blockIdx.x * 256 + threadIdx.x; // 4096
  const int b = idx >> 10, d = idx & 1023;
  float s = 0.f;
  for (int g = 0; g < 64; ++g) s += part[((size_t)b * 64 + g) * kDModel + d];
  mean[idx] = s * (1.f / kSeq);
}

// ---------------- router MLP + softmax ----------------
__global__ __launch_bounds__(128) void k_router(const float* __restrict__ mean,
                                                const float* __restrict__ w1,
                                                const float* __restrict__ b1,
                                                const float* __restrict__ w2,
                                                const float* __restrict__ b2,
                                                float* __restrict__ pfm) {
  __shared__ float hbuf[4][32];
  __shared__ float logit[4][3];
  const int t = threadIdx.x;
  {
    int b = t >> 5, j = t & 31;
    float s = b1[j];
    for (int d = 0; d < kDModel; ++d) s += mean[b * kDModel + d] * w1[j * kDModel + d];
    hbuf[b][j] = siluf(s);
  }
  __syncthreads();
  if (t < 12) {
    int b = t / 3, k = t % 3;
    float s = b2[k];
    for (int j = 0; j < 32; ++j) s += hbuf[b][j] * w2[k * 32 + j];
    logit[b][k] = s;
  }
  __syncthreads();
  if (t < 4) {
    float m = fmaxf(logit[t][0], fmaxf(logit[t][1], logit[t][2]));
    float e0 = expf(logit[t][0] - m), e1 = expf(logit[t][1] - m), e2 = expf(logit[t][2] - m);
    float inv = 1.f / (e0 + e1 + e2);
    pfm[t] = e0 * inv;            // p_fast[b]
    pfm[4 + t] = (e1 + e2) * inv; // p_mamba[b]
  }
}

// ---------------- weight casts ----------------
__global__ __launch_bounds__(256) void k_castpad_w1(const float* __restrict__ w,
                                                    bf16* __restrict__ wb) {
  const size_t idx = (size_t)blockIdx.x * 256 + threadIdx.x; // over 4352*1024
  const int row = (int)(idx >> 10);
  wb[idx] = (bf16)(row < kDInProj ? w[idx] : 0.f);
}

__global__ __launch_bounds__(256) void k_cast_w2(const float* __restrict__ w,
                                                 bf16* __restrict__ wb) {
  const size_t i4 = (size_t)blockIdx.x * 256 + threadIdx.x;
  float4 v = ((const float4*)w)[i4];
  bf16x4 o;
  o[0] = (bf16)v.x; o[1] = (bf16)v.y; o[2] = (bf16)v.z; o[3] = (bf16)v.w;
  ((bf16x4*)wb)[i4] = o;
}

// ====== bf16 GEMM: C[m][n] = sum_k A[m,k]*B[n,k], BK=32, dbuf, swizzled ======
// Per-wave output 64x64 (64 acc VGPR) so VGPR<=128 -> 4 waves/SIMD -> >=2
// blocks/CU co-resident (m114 overlap hides barrier drains).
// LDS layout: row-pairs packed into 128B lines; slot = ((r&1)*4+kb) ^ (line&7)
// -> 64 lanes hit 64 distinct 16B slots (minimum-cycle LDS access). Same
// involution applied to stage source (global) and ds_read (rule #21).
template <int WM, int WN, int NF>
__global__ __launch_bounds__(WM * WN * 64, 4) void k_gemm(
    const bf16* __restrict__ A, const bf16* __restrict__ B,
    bf16* __restrict__ Cb, int K, int Nreal, int ldc, int ntn) {
  constexpr int THREADS = WM * WN * 64;
  constexpr int BM = WM * 64;       // 4 m-frags per wave
  constexpr int BN = WN * NF * 16;
  constexpr int NA = (BM * 4) / THREADS; // A gloads/thread/K-tile
  constexpr int NB = (BN * 4) / THREADS;
  __shared__ __align__(16) bf16 Al[2][BM / 2][64];
  __shared__ __align__(16) bf16 Bl[2][BN / 2][64];
  const int tid = threadIdx.x;
  const int lane = tid & 63, wid = tid >> 6;
  const int wr = wid / WN, wc = wid % WN;
  const int lr = lane & 15, kb = lane >> 4;
  const int cpx = (int)gridDim.x >> 3;
  const int bid = ((int)blockIdx.x & 7) * cpx + ((int)blockIdx.x >> 3);
  const long n0 = (long)(bid % ntn) * BN;
  const long m0 = (long)(bid / ntn) * BM;

  f32x4 acc[4][NF];
#pragma unroll
  for (int i = 0; i < 4; ++i)
#pragma unroll
    for (int j = 0; j < NF; ++j) acc[i][j] = (f32x4){0.f, 0.f, 0.f, 0.f};

  const int nkt = K >> 5;

  // stage K-tile kt into buffer pp. LDS dest linear (idx*16); source address
  // carries the inverse swizzle: slot(line,s) holds row=2*line+(s^line&7)/4,
  // chunk=(s^line&7)&3.
#define STAGE(pp, kt)                                                          \
  {                                                                            \
    const long koff = (long)(kt)*32;                                           \
    _Pragma("unroll") for (int j = 0; j < NA; ++j) {                           \
      int idx = j * THREADS + tid;                                             \
      int line = idx >> 3, sp = (idx & 7) ^ (line & 7);                        \
      int row = line * 2 + (sp >> 2), ch = sp & 3;                             \
      __builtin_amdgcn_global_load_lds(                                        \
          (const AS1 void*)(A + (m0 + row) * K + koff + ch * 8),               \
          (AS3 void*)((char*)&Al[pp][0][0] + idx * 16), 16, 0, 0);             \
    }                                                                          \
    _Pragma("unroll") for (int j = 0; j < NB; ++j) {                           \
      int idx = j * THREADS + tid;                                             \
      int line = idx >> 3, sp = (idx & 7) ^ (line & 7);                        \
      int row = line * 2 + (sp >> 2), ch = sp & 3;                             \
      __builtin_amdgcn_global_load_lds(                                        \
          (const AS1 void*)(B + (n0 + row) * K + koff + ch * 8),               \
          (AS3 void*)((char*)&Bl[pp][0][0] + idx * 16), 16, 0, 0);             \
    }                                                                          \
  }
  // swizzled read of 16B frag: row r, k-chunk kb
#define LOFF(r) (((r) >> 1) * 128 + (((((r)&1) << 2) | kb) ^ (((r) >> 1) & 7)) * 16)
#define RDA(pp, r) (*(const bf16x8*)((const char*)&Al[pp][0][0] + LOFF(r)))
#define RDB(pp, r) (*(const bf16x8*)((const char*)&Bl[pp][0][0] + LOFF(r)))

  bf16x8 bfr[NF];
  bf16x8 af[2];

  STAGE(0, 0);
  __syncthreads(); // vmcnt(0) drain: stage(0) landed
#pragma unroll
  for (int nf = 0; nf < NF; ++nf) bfr[nf] = RDB(0, wc * 64 + nf * 16 + lr);
  af[0] = RDA(0, wr * 64 + lr);

  for (int t = 0; t < nkt; ++t) {
    const int p = t & 1;
    if (t + 1 < nkt) STAGE(p ^ 1, t + 1); // buffer p^1 fully consumed at t-1
#pragma unroll
    for (int q = 0; q < 4; ++q) {
      if (q < 3) af[(q + 1) & 1] = RDA(p, wr * 64 + (q + 1) * 16 + lr);
      __builtin_amdgcn_s_setprio(1);
#pragma unroll
      for (int nf = 0; nf < NF; ++nf)
        acc[q][nf] = __builtin_amdgcn_mfma_f32_16x16x32_bf16(af[q & 1], bfr[nf],
                                                             acc[q][nf], 0, 0, 0);
      __builtin_amdgcn_s_setprio(0);
    }
    if (t + 1 < nkt) {
      __syncthreads(); // stage(t+1) landed; all waves done with buf p
#pragma unroll
      for (int nf = 0; nf < NF; ++nf) bfr[nf] = RDB(p ^ 1, wc * 64 + nf * 16 + lr);
      af[0] = RDA(p ^ 1, wr * 64 + lr);
    }
  }
#undef STAGE
#undef LOFF
#undef RDA
#undef RDB

  const int rr = kb * 4;
#pragma unroll
  for (int mf = 0; mf < 4; ++mf) {
#pragma unroll
    for (int nf = 0; nf < NF; ++nf) {
      int col = (int)n0 + wc * 64 + nf * 16 + lr;
      if (col < Nreal) {
        long rbase = m0 + wr * 64 + mf * 16 + rr;
#pragma unroll
        for (int j = 0; j < 4; ++j)
          Cb[(rbase + j) * (long)ldc + col] = (bf16)acc[mf][nf][j];
      }
    }
  }
}

// ------- causal depthwise conv1d (k=4) + bias + SiLU, vectorized bf16x8 -----
__global__ __launch_bounds__(256) void k_conv(const bf16* __restrict__ zx,
                                              const float* __restrict__ cw,
                                              const float* __restrict__ cb,
                                              bf16* __restrict__ xbc) {
  const int gid = blockIdx.x * 256 + threadIdx.x;
  if (gid >= kRows * 272) return; // 272 = 2176/8 chunks per row
  const int row = gid / 272;
  const int cg = gid - row * 272;
  const int c0 = cg * 8;
  const int s = row & (kSeq - 1);
  const bf16* base = zx + (size_t)row * kDInProj + kDInner + c0;
  bf16x8 z8 = {};
  bf16x8 r3 = *(const bf16x8*)(base);
  bf16x8 r2 = (s >= 1) ? *(const bf16x8*)(base - kDInProj) : z8;
  bf16x8 r1 = (s >= 2) ? *(const bf16x8*)(base - 2 * kDInProj) : z8;
  bf16x8 r0 = (s >= 3) ? *(const bf16x8*)(base - 3 * kDInProj) : z8;
  bf16x8 o;
#pragma unroll
  for (int e = 0; e < 8; ++e) {
    float4 w = ((const float4*)cw)[c0 + e];
    float a = cb[c0 + e] + w.x * (float)r0[e] + w.y * (float)r1[e] +
              w.z * (float)r2[e] + w.w * (float)r3[e];
    o[e] = (bf16)siluf(a);
  }
  *(bf16x8*)(xbc + (size_t)row * kConvDim + c0) = o;
}

// ---------------- dt = softplus, ldA = dt*A (log decay) ----------------
__global__ __launch_bounds__(256) void k_dtda(const bf16* __restrict__ zx,
                                              const float* __restrict__ dt_bias,
                                              const float* __restrict__ A_log,
                                              float* __restrict__ dt, float* __restrict__ ldA) {
  const int idx = blockIdx.x * 256 + threadIdx.x;
  const int row = idx >> 5, hh = idx & 31;
  float raw = (float)zx[(size_t)row * kDInProj + (kDInner + kConvDim) + hh] + dt_bias[hh];
  float dtv = (raw > 20.f) ? raw : log1pf(expf(raw));
  dt[idx] = dtv;
  ldA[idx] = dtv * -expf(A_log[hh]);
}

// ================= chunked SSD scan =================
__global__ __launch_bounds__(256) void k_chunkA(
    const bf16* __restrict__ xbc, const float* __restrict__ dtb,
    const float* __restrict__ ldab, float* __restrict__ cumbuf,
    float* __restrict__ Tc, bf16* __restrict__ yb, bf16* __restrict__ Sbuf) {
  const int c = blockIdx.x, h = blockIdx.y, b = blockIdx.z;
  const int tid = threadIdx.x;
  const int w = tid >> 6, lane = tid & 63, lr = lane & 15, kb = lane >> 4;
  const int rr = kb * 4;
  const int t0 = c * kChunk;
  __shared__ bf16 Bl[64 * 72], Cl[64 * 72], XT[64 * 72], WBT[64 * 72], Ml[64 * 72];
  __shared__ float cum_s[64], dt_s[64], w_s[64];

  { // stage B, C (row-major) and X^T
    int s = tid >> 2, q = tid & 3;
    const bf16* rowp = xbc + ((size_t)b * kSeq + t0 + s) * kConvDim;
    bf16x8 x0 = *(const bf16x8*)(rowp + h * 64 + q * 16);
    bf16x8 x1 = *(const bf16x8*)(rowp + h * 64 + q * 16 + 8);
    bf16x8 b0 = *(const bf16x8*)(rowp + kDInner + q * 16);
    bf16x8 b1 = *(const bf16x8*)(rowp + kDInner + q * 16 + 8);
    bf16x8 c0 = *(const bf16x8*)(rowp + kDInner + 64 + q * 16);
    bf16x8 c1 = *(const bf16x8*)(rowp + kDInner + 64 + q * 16 + 8);
    *(bf16x8*)(Bl + s * 72 + q * 16) = b0;
    *(bf16x8*)(Bl + s * 72 + q * 16 + 8) = b1;
    *(bf16x8*)(Cl + s * 72 + q * 16) = c0;
    *(bf16x8*)(Cl + s * 72 + q * 16 + 8) = c1;
#pragma unroll
    for (int e = 0; e < 8; ++e) XT[(q * 16 + e) * 72 + s] = x0[e];
#pragma unroll
    for (int e = 0; e < 8; ++e) XT[(q * 16 + 8 + e) * 72 + s] = x1[e];
  }
  if (tid < 64) { // wave 0: inclusive prefix of ldA
    size_t di = ((size_t)b * kSeq + t0 + tid) * kHeads + h;
    float v = ldab[di];
    float dtv = dtb[di];
#pragma unroll
    for (int o = 1; o < 64; o <<= 1) {
      float u = __shfl_up(v, o);
      if (lane >= o) v += u;
    }
    cum_s[tid] = v;
    dt_s[tid] = dtv;
    float tot = __shfl(v, 63);
    w_s[tid] = expf(tot - v) * dtv;
    cumbuf[(((size_t)b * kHeads + h) * kNChunk + c) * 64 + tid] = v;
    if (tid == 63) Tc[(b * kHeads + h) * kNChunk + c] = expf(v);
  }
  __syncthreads();

  // WBT[n][s] = B[s][n] * w[s]
#pragma unroll
  for (int i = 0; i < 16; ++i) {
    int e = i * 256 + tid;
    int n = e >> 6, s = e & 63;
    WBT[n * 72 + s] = (bf16)((float)Bl[s * 72 + n] * w_s[s]);
  }

  // GEMM1: G[t,s] = sum_n C[t,n] B[s,n]
  f32x4 g[4];
#pragma unroll
  for (int nt = 0; nt < 4; ++nt) g[nt] = (f32x4){0.f, 0.f, 0.f, 0.f};
#pragma unroll
  for (int kk = 0; kk < 2; ++kk) {
    bf16x8 a = *(const bf16x8*)(Cl + (w * 16 + lr) * 72 + kk * 32 + kb * 8);
#pragma unroll
    for (int nt = 0; nt < 4; ++nt) {
      bf16x8 bb = *(const bf16x8*)(Bl + (nt * 16 + lr) * 72 + kk * 32 + kb * 8);
      g[nt] = __builtin_amdgcn_mfma_f32_16x16x32_bf16(a, bb, g[nt], 0, 0, 0);
    }
  }
#pragma unroll
  for (int nt = 0; nt < 4; ++nt)
#pragma unroll
    for (int j = 0; j < 4; ++j) {
      int tt = w * 16 + rr + j, ss = nt * 16 + lr;
      float m = (ss <= tt) ? g[nt][j] * expf(cum_s[tt] - cum_s[ss]) * dt_s[ss] : 0.f;
      Ml[tt * 72 + ss] = (bf16)m;
    }
  __syncthreads();

  // GEMM2: Y_intra[t,p] = sum_s M[t,s] x[s,p]
  f32x4 y4[4];
#pragma unroll
  for (int pt = 0; pt < 4; ++pt) y4[pt] = (f32x4){0.f, 0.f, 0.f, 0.f};
#pragma unroll
  for (int kk = 0; kk < 2; ++kk) {
    bf16x8 a = *(const bf16x8*)(Ml + (w * 16 + lr) * 72 + kk * 32 + kb * 8);
#pragma unroll
    for (int pt = 0; pt < 4; ++pt) {
      bf16x8 bb = *(const bf16x8*)(XT + (pt * 16 + lr) * 72 + kk * 32 + kb * 8);
      y4[pt] = __builtin_amdgcn_mfma_f32_16x16x32_bf16(a, bb, y4[pt], 0, 0, 0);
    }
  }
#pragma unroll
  for (int pt = 0; pt < 4; ++pt)
#pragma unroll
    for (int j = 0; j < 4; ++j) {
      int tt = w * 16 + rr + j, pp = pt * 16 + lr;
      yb[((size_t)b * kSeq + t0 + tt) * kDInner + h * 64 + pp] = (bf16)y4[pt][j];
    }

  // GEMM3: S[p,n] = sum_s x[s,p] w[s] B[s,n]
  f32x4 s4[4];
#pragma unroll
  for (int nt = 0; nt < 4; ++nt) s4[nt] = (f32x4){0.f, 0.f, 0.f, 0.f};
#pragma unroll
  for (int kk = 0; kk < 2; ++kk) {
    bf16x8 a = *(const bf16x8*)(XT + (w * 16 + lr) * 72 + kk * 32 + kb * 8);
#pragma unroll
    for (int nt = 0; nt < 4; ++nt) {
      bf16x8 bb = *(const bf16x8*)(WBT + (nt * 16 + lr) * 72 + kk * 32 + kb * 8);
      s4[nt] = __builtin_amdgcn_mfma_f32_16x16x32_bf16(a, bb, s4[nt], 0, 0, 0);
    }
  }
  const size_t sbase = (((size_t)b * kHeads + h) * kNChunk + c) * 4096;
#pragma unroll
  for (int nt = 0; nt < 4; ++nt)
#pragma unroll
    for (int j = 0; j < 4; ++j) {
      int pp = w * 16 + rr + j, nn = nt * 16 + lr;
      Sbuf[sbase + pp * 64 + nn] = (bf16)s4[nt][j];
    }
}

// Pass B: serial scan over 32 chunks, in-place (bf16 states, fp32 accum)
__global__ __launch_bounds__(256) void k_chunkB(bf16* __restrict__ S,
                                                const float* __restrict__ Tc) {
  const int gid = blockIdx.x * 256 + threadIdx.x;
  const int bh = gid >> 10;
  const int pn = (gid & 1023) << 2;
  bf16* base = S + (size_t)bh * kNChunk * 4096 + pn;
  const float* tc = Tc + bh * kNChunk;
  float4 hh = {0.f, 0.f, 0.f, 0.f};
  bf16x4 s = *(const bf16x4*)(base);
  for (int c = 0; c < kNChunk; ++c) {
    bf16x4 sn = {};
    if (c + 1 < kNChunk) sn = *(const bf16x4*)(base + (size_t)(c + 1) * 4096);
    float t = tc[c];
    bf16x4 ho;
    ho[0] = (bf16)hh.x; ho[1] = (bf16)hh.y; ho[2] = (bf16)hh.z; ho[3] = (bf16)hh.w;
    *(bf16x4*)(base + (size_t)c * 4096) = ho;
    hh.x = t * hh.x + (float)s[0];
    hh.y = t * hh.y + (float)s[1];
    hh.z = t * hh.z + (float)s[2];
    hh.w = t * hh.w + (float)s[3];
    s = sn;
  }
}

// Pass C: y += exp(cum[t]) * C[t]·h0[p,:] + D*x
__global__ __launch_bounds__(256) void k_chunkC(
    const bf16* __restrict__ xbc, const float* __restrict__ cumbuf,
    const bf16* __restrict__ hs, const float* __restrict__ Dp,
    bf16* __restrict__ yb) {
  const int c = blockIdx.x, h = blockIdx.y, b = blockIdx.z;
  const int tid = threadIdx.x;
  const int w = tid >> 6, lane = tid & 63, lr = lane & 15, kb = lane >> 4;
  const int rr = kb * 4;
  const int t0 = c * kChunk;
  __shared__ bf16 Cl[64 * 72];
  __shared__ float ecum[64];
  {
    int s = tid >> 2, q = tid & 3;
    const bf16* rowp = xbc + ((size_t)b * kSeq + t0 + s) * kConvDim + kDInner + 64 + q * 16;
    *(bf16x8*)(Cl + s * 72 + q * 16) = *(const bf16x8*)rowp;
    *(bf16x8*)(Cl + s * 72 + q * 16 + 8) = *(const bf16x8*)(rowp + 8);
  }
  if (tid < 64)
    ecum[tid] = expf(cumbuf[(((size_t)b * kHeads + h) * kNChunk + c) * 64 + tid]);
  __syncthreads();

  const bf16* hbase = hs + (((size_t)b * kHeads + h) * kNChunk + c) * 4096;
  f32x4 acc[4];
#pragma unroll
  for (int pt = 0; pt < 4; ++pt) acc[pt] = (f32x4){0.f, 0.f, 0.f, 0.f};
#pragma unroll
  for (int kk = 0; kk < 2; ++kk) {
    bf16x8 a = *(const bf16x8*)(Cl + (w * 16 + lr) * 72 + kk * 32 + kb * 8);
#pragma unroll
    for (int pt = 0; pt < 4; ++pt) {
      bf16x8 bb = *(const bf16x8*)(hbase + (pt * 16 + lr) * 64 + kk * 32 + kb * 8);
      acc[pt] = __builtin_amdgcn_mfma_f32_16x16x32_bf16(a, bb, acc[pt], 0, 0, 0);
    }
  }
  const float Dh = Dp[h];
#pragma unroll
  for (int pt = 0; pt < 4; ++pt)
#pragma unroll
    for (int j = 0; j < 4; ++j) {
      int tt = w * 16 + rr + j, pp = pt * 16 + lr;
      size_t ri = (size_t)b * kSeq + t0 + tt;
      size_t yi = ri * kDInner + h * 64 + pp;
      float xv = (float)xbc[ri * kConvDim + h * 64 + pp];
      yb[yi] = (bf16)((float)yb[yi] + ecum[tt] * acc[pt][j] + Dh * xv);
    }
}

// ---------------- gated RMSNorm: yg = rmsnorm(y*silu(z)) * gw ----------------
__global__ __launch_bounds__(256) void k_gnorm(const bf16* __restrict__ y,
                                               const bf16* __restrict__ zx,
                                               const float* __restrict__ gw,
                                               bf16* __restrict__ yg) {
  const int row = blockIdx.x;
  const int tid = threadIdx.x;
  const int c0 = tid * 8;
  bf16x8 yv = *(const bf16x8*)(y + (size_t)row * kDInner + c0);
  bf16x8 zv = *(const bf16x8*)(zx + (size_t)row * kDInProj + c0);
  float v[8];
  float ss = 0.f;
#pragma unroll
  for (int j = 0; j < 8; ++j) {
    float val = (float)yv[j] * siluf((float)zv[j]);
    v[j] = val;
    ss += val * val;
  }
  __shared__ float red[4];
  ss = block_reduce_sum(ss, red, tid);
  float scale = rsqrtf(ss * (1.f / kDInner) + kGnEps);
  bf16x8 ov;
#pragma unroll
  for (int j = 0; j < 8; ++j) ov[j] = (bf16)(v[j] * scale * gw[c0 + j]);
  *(bf16x8*)(yg + (size_t)row * kDInner + c0) = ov;
}

// ---------------- final combine ----------------
__global__ __launch_bounds__(256) void k_combine(const float* __restrict__ x,
                                                 const float* __restrict__ nw,
                                                 const bf16* __restrict__ mo,
                                                 const float* __restrict__ pfm,
                                                 float* __restrict__ out) {
  const int row = blockIdx.x;
  const int tid = threadIdx.x;
  const int b = row >> 11;
  float4 v = ((const float4*)(x + (size_t)row * kDModel))[tid];
  __shared__ float red[4];
  float ss = block_reduce_sum(v.x * v.x + v.y * v.y + v.z * v.z + v.w * v.w, red, tid);
  float scale = rsqrtf(ss * (1.f / kDModel) + kRmsEps);
  float pf = pfm[b], pm = pfm[4 + b];
  float4 wv = ((const float4*)nw)[tid];
  bf16x4 mv = *(const bf16x4*)(mo + (size_t)row * kDModel + tid * 4);
  float4 o;
  o.x = v.x + pf * (v.x * scale * wv.x) + pm * (float)mv[0];
  o.y = v.y + pf * (v.y * scale * wv.y) + pm * (float)mv[1];
  o.z = v.z + pf * (v.z * scale * wv.z) + pm * (float)mv[2];
  o.w = v.w + pf * (v.w * scale * wv.w) + pm * (float)mv[3];
  ((float4*)(out + (size_t)row * kDModel))[tid] = o;
}

extern "C" void kernel_launch(void* const* d_in, const int* in_sizes, int n_in,
                              void* d_out, int out_size, void* d_ws, size_t ws_size,
                              hipStream_t stream) {
  const float* x = (const float*)d_in[0];
  const float* norm_w = (const float*)d_in[1];
  const float* r_w1 = (const float*)d_in[2];
  const float* r_b1 = (const float*)d_in[3];
  const float* r_w2 = (const float*)d_in[4];
  const float* r_b2 = (const float*)d_in[5];
  const float* in_proj_w = (const float*)d_in[6];
  const float* conv_w = (const float*)d_in[7];
  const float* conv_b = (const float*)d_in[8];
  const float* dt_bias = (const float*)d_in[9];
  const float* A_log = (const float*)d_in[10];
  const float* D_param = (const float*)d_in[11];
  const float* gnorm_w = (const float*)d_in[12];
  const float* out_proj_w = (const float*)d_in[13];
  float* out = (float*)d_out;
  char* ws = (char*)d_ws;

  // workspace layout (~207 MB)
  bf16* xnb     = (bf16*)(ws + 0);           // 16,777,216
  bf16* w1b     = (bf16*)(ws + 16777216);    //  8,912,896
  bf16* zx      = (bf16*)(ws + 25690112);    // 69,730,304
  bf16* xbc     = (bf16*)(ws + 95420416);    // 35,651,584
  float* dtb    = (float*)(ws + 131072000);  //  1,048,576
  float* ldab   = (float*)(ws + 132120576);  //  1,048,576
  float* cumbuf = (float*)(ws + 133169152);  //  1,048,576
  float* Tcb    = (float*)(ws + 134217728);  //     16,384
  bf16* yb      = (bf16*)(ws + 134234112);   // 33,554,432
  bf16* Sbuf    = (bf16*)(ws + 167788544);   // 33,554,432
  bf16* yg      = (bf16*)(ws + 167788544);   // aliases Sbuf (dead after passC)
  bf16* w2b     = (bf16*)(ws + 201342976);   //  4,194,304
  float* part   = (float*)(ws + 205537280);  //  1,048,576
  float* meanb  = (float*)(ws + 206585856);  //     16,384
  float* pfm    = (float*)(ws + 206602240);  //         32
  bf16* mo      = (bf16*)(ws + 95420416);    // aliases xbc (dead after passC)

  k_rmsnorm<<<kRows, 256, 0, stream>>>(x, norm_w, xnb);
  k_pool1<<<dim3(64, 4), 128, 0, stream>>>(xnb, part);
  k_pool2<<<16, 256, 0, stream>>>(part, meanb);
  k_router<<<1, 128, 0, stream>>>(meanb, r_w1, r_b1, r_w2, r_b2, pfm);
  k_castpad_w1<<<kNPad1 * kDModel / 256, 256, 0, stream>>>(in_proj_w, w1b);
  k_cast_w2<<<kDModel * kDInner / 1024, 256, 0, stream>>>(out_proj_w, w2b);
  // zxbcdt = x_norm @ in_proj_w.T  [8192 x 4256] ; BM=128,BN=256: 64*17=1088
  k_gemm<2, 4, 4><<<(kRows / 128) * (kNPad1 / 256), 512, 0, stream>>>(
      xnb, w1b, zx, kDModel, kDInProj, kDInProj, kNPad1 / 256);
  k_conv<<<kRows * 272 / 256, 256, 0, stream>>>(zx, conv_w, conv_b, xbc);
  k_dtda<<<kRows * kHeads / 256, 256, 0, stream>>>(zx, dt_bias, A_log, dtb, ldab);
  k_chunkA<<<dim3(kNChunk, kHeads, kBatch), 256, 0, stream>>>(
      xbc, dtb, ldab, cumbuf, Tcb, yb, Sbuf);
  k_chunkB<<<512, 256, 0, stream>>>(Sbuf, Tcb);
  k_chunkC<<<dim3(kNChunk, kHeads, kBatch), 256, 0, stream>>>(
      xbc, cumbuf, Sbuf, D_param, yb);
  k_gnorm<<<kRows, 256, 0, stream>>>(yb, zx, gnorm_w, yg);
  // mamba_out = yg @ out_proj_w.T  [8192 x 1024] ; BM=128,BN=128: 64*8=512
  k_gemm<2, 2, 4><<<(kRows / 128) * (kDModel / 128), 256, 0, stream>>>(
      yg, w2b, mo, kDInner, kDModel, kDModel, kDModel / 128);
  k_combine<<<kRows, 256, 0, stream>>>(x, norm_w, mo, pfm, out);
}